// Round 5
// baseline (225.981 us; speedup 1.0000x reference)
//
#include <hip/hip_runtime.h>

// NGP hash-grid encode + fused MLP (16->64->32->2, leaky_relu 0.01)
// N=524288 points, L=8 levels, T=65536 table entries, F=2 features.
// Outputs (concat flat): sigma_clipped[N], alpha_scaled[N], zeros[N].
//
// R5: (a) __builtin_amdgcn_sched_barrier(0) between issuing all 64 hash
// gathers and consuming them -- an MIR fence NOTHING can cross, unlike
// R3's asm memory clobber which consumers hoisted across (VGPR stayed
// 44 = loads re-sunk to uses). (b) packed-fp32 math (v_pk_fma_f32 via
// <2 x float> __builtin_elementwise_fma) halves VALU issue in the MLP.
// No inline asm (R4's asm loads aborted the process).

#define NPTS 524288
#define TTAB 65536
#define PI2 2654435761u
#define PI3 805459861u

typedef float vf2 __attribute__((ext_vector_type(2)));

__global__ __launch_bounds__(256, 2) void ngp_kernel(
    const float* __restrict__ x,
    const float* __restrict__ gridp,
    const float* __restrict__ w0,
    const float* __restrict__ b0,
    const float* __restrict__ w1,
    const float* __restrict__ b1,
    const float* __restrict__ w2,
    const float* __restrict__ b2,
    float* __restrict__ out)
{
    // Weights staged in LDS; w0 transposed to [j][k] so the 16 inputs for
    // output-neuron j are contiguous (ds_read_b128). w1 rows contiguous.
    // All in-loop weight reads are wave-uniform -> LDS broadcast (free).
    __shared__ __align__(16) float sw0t[64 * 16];
    __shared__ __align__(16) float sw1[64 * 32];
    __shared__ __align__(16) float sw2t[64];   // [m][k] m=0,1 k=0..31
    __shared__ __align__(16) float sb0[64];
    __shared__ __align__(16) float sb1[32];
    __shared__ __align__(16) float sb2[2];

    const int tid = threadIdx.x;

    for (int i = tid; i < 64 * 16; i += 256) {
        int k = i >> 6, j = i & 63;          // w0 is (16,64) row-major: w0[k][j]
        sw0t[j * 16 + k] = w0[i];
    }
    for (int i = tid; i < 64 * 32; i += 256) sw1[i] = w1[i];
    if (tid < 64) {
        sw2t[(tid & 1) * 32 + (tid >> 1)] = w2[tid];  // w2 (32,2) -> w2t[m][k]
        sb0[tid] = b0[tid];
    }
    if (tid < 32) sb1[tid] = b1[tid];
    if (tid < 2)  sb2[tid] = b2[tid];
    __syncthreads();

    const int n = blockIdx.x * 256 + tid;
    const float px = x[n * 3 + 0];
    const float py = x[n * 3 + 1];
    const float pz = x[n * 3 + 2];

    const float levels[8] = {2.0f, 2.6946f, 3.6301f, 4.8907f,
                             6.5893f, 8.8766f, 11.959f, 16.111f};

    const vf2* __restrict__ gtab = (const vf2*)gridp;

    // Phase 1: all hash bases + fractions (cheap VALU, no memory).
    float fxs[8], fys[8], fzs[8];
    unsigned hb[8];
    #pragma unroll
    for (int l = 0; l < 8; ++l) {
        const float lev = levels[l];
        float xs0 = px * lev, xs1 = py * lev, xs2 = pz * lev;
        float fl0 = floorf(xs0), fl1 = floorf(xs1), fl2 = floorf(xs2);
        fxs[l] = xs0 - fl0;
        fys[l] = xs1 - fl1;
        fzs[l] = xs2 - fl2;
        unsigned cx = (unsigned)(int)fl0;
        unsigned cy = (unsigned)(int)fl1;
        unsigned cz = (unsigned)(int)fl2;
        hb[l] = cx + cy * PI2 + cz * PI3;   // mod 2^32 wrap == jnp.uint32
    }

    // Phase 2: issue all 64 gathers. Corner hash deltas fold to constants.
    vf2 feats[64];
    #pragma unroll
    for (int l = 0; l < 8; ++l) {
        const unsigned hbase = hb[l];
        #pragma unroll
        for (int c = 0; c < 8; ++c) {
            const int oi = (c >> 2) & 1;   // OFFSETS order: i outer, k inner
            const int oj = (c >> 1) & 1;
            const int ok = c & 1;
            unsigned idx = (hbase + (unsigned)oi + (unsigned)oj * PI2
                                  + (unsigned)ok * PI3) & (TTAB - 1u);
            feats[l * 8 + c] = gtab[l * TTAB + (int)idx];
        }
    }

    // MIR scheduling fence: no instruction may cross. Loads above cannot
    // sink to their uses; consumers below cannot hoist between loads.
    // => all 64 loads in flight, one latency exposure per thread.
    __builtin_amdgcn_sched_barrier(0);

    // Phase 3: consume; trilinear blend in packed fp32 (feats are pairs).
    vf2 enc2[8];
    #pragma unroll
    for (int l = 0; l < 8; ++l) {
        const float fx = fxs[l], fy = fys[l], fz = fzs[l];
        const float gx = 1.f - fx, gy = 1.f - fy, gz = 1.f - fz;
        const float w00 = gx * gy, w01 = gx * fy, w10 = fx * gy, w11 = fx * fy;
        float cw[8] = {w00 * gz, w00 * fz, w01 * gz, w01 * fz,
                       w10 * gz, w10 * fz, w11 * gz, w11 * fz};
        vf2 e = {0.f, 0.f};
        #pragma unroll
        for (int c = 0; c < 8; ++c) {
            vf2 wv = {cw[c], cw[c]};
            e = __builtin_elementwise_fma(wv, feats[l * 8 + c], e);
        }
        enc2[l] = e;
    }

    // Fused MLP: layer0 (16->64) + leaky, streamed into layer1 accumulators
    // (64->32, packed pairs) so h0 never materializes.
    vf2 h1[16];
    #pragma unroll
    for (int k = 0; k < 16; ++k) h1[k] = (vf2){0.f, 0.f};

    #pragma unroll 4
    for (int j = 0; j < 64; ++j) {
        const float4* __restrict__ wr = (const float4*)&sw0t[j * 16];
        float4 q0 = wr[0], q1 = wr[1], q2 = wr[2], q3 = wr[3];
        vf2 acc = {sb0[j], 0.f};
        acc = __builtin_elementwise_fma(enc2[0], (vf2){q0.x, q0.y}, acc);
        acc = __builtin_elementwise_fma(enc2[1], (vf2){q0.z, q0.w}, acc);
        acc = __builtin_elementwise_fma(enc2[2], (vf2){q1.x, q1.y}, acc);
        acc = __builtin_elementwise_fma(enc2[3], (vf2){q1.z, q1.w}, acc);
        acc = __builtin_elementwise_fma(enc2[4], (vf2){q2.x, q2.y}, acc);
        acc = __builtin_elementwise_fma(enc2[5], (vf2){q2.z, q2.w}, acc);
        acc = __builtin_elementwise_fma(enc2[6], (vf2){q3.x, q3.y}, acc);
        acc = __builtin_elementwise_fma(enc2[7], (vf2){q3.z, q3.w}, acc);
        float a = acc.x + acc.y;
        a = fmaf(0.01f, fminf(a, 0.f), fmaxf(a, 0.f));   // leaky_relu

        vf2 av = {a, a};
        const float4* __restrict__ w1r = (const float4*)&sw1[j * 32];
        #pragma unroll
        for (int k4 = 0; k4 < 8; ++k4) {
            float4 ww = w1r[k4];
            h1[k4 * 2 + 0] = __builtin_elementwise_fma(av, (vf2){ww.x, ww.y},
                                                       h1[k4 * 2 + 0]);
            h1[k4 * 2 + 1] = __builtin_elementwise_fma(av, (vf2){ww.z, ww.w},
                                                       h1[k4 * 2 + 1]);
        }
    }

    // Layer 2: 32 -> 2 (packed pairs, horizontal add at the end).
    const vf2* __restrict__ b1p = (const vf2*)sb1;
    const vf2* __restrict__ w20 = (const vf2*)&sw2t[0];
    const vf2* __restrict__ w21 = (const vf2*)&sw2t[32];
    vf2 s0v = {0.f, 0.f}, s1v = {0.f, 0.f};
    const vf2 zero2 = {0.f, 0.f};
    const vf2 slope2 = {0.01f, 0.01f};
    #pragma unroll
    for (int k = 0; k < 16; ++k) {
        vf2 hk = h1[k] + b1p[k];
        vf2 pos = __builtin_elementwise_max(hk, zero2);
        vf2 neg = __builtin_elementwise_min(hk, zero2);
        hk = __builtin_elementwise_fma(slope2, neg, pos);   // leaky_relu
        s0v = __builtin_elementwise_fma(hk, w20[k], s0v);
        s1v = __builtin_elementwise_fma(hk, w21[k], s1v);
    }
    float s0 = s0v.x + s0v.y + sb2[0];
    float s1 = s1v.x + s1v.y + sb2[1];

    // Epilogue: sigma clip, alpha scale, zeros.
    out[n]            = (s0 > -1.0f) ? s0 : 0.0f;
    out[NPTS + n]     = fminf(0.0f, s1) * 0.1f;
    out[2 * NPTS + n] = 0.0f;
}

extern "C" void kernel_launch(void* const* d_in, const int* in_sizes, int n_in,
                              void* d_out, int out_size, void* d_ws, size_t ws_size,
                              hipStream_t stream) {
    const float* x    = (const float*)d_in[0];
    const float* grid = (const float*)d_in[1];
    const float* w0   = (const float*)d_in[2];
    const float* b0   = (const float*)d_in[3];
    const float* w1   = (const float*)d_in[4];
    const float* b1   = (const float*)d_in[5];
    const float* w2   = (const float*)d_in[6];
    const float* b2   = (const float*)d_in[7];
    float* out = (float*)d_out;

    ngp_kernel<<<NPTS / 256, 256, 0, stream>>>(x, grid, w0, b0, w1, b1, w2, b2, out);
}

// Round 6
// 160.560 us; speedup vs baseline: 1.4075x; 1.4075x over previous
//
#include <hip/hip_runtime.h>

// NGP hash-grid encode + fused MLP (16->64->32->2, leaky_relu 0.01)
// N=524288 points, L=8 levels, T=65536 table entries, F=2 features.
// Outputs (concat flat): sigma_clipped[N], alpha_scaled[N], zeros[N].
//
// R6: halve divergent gather requests. R1 vs R5 showed the gather pipe
// is THROUGHPUT-bound (~0.33 lane-req/cyc/CU regardless of 2 or 50
// loads in flight), so the only lever is fewer requests. Corners
// differing in the x-offset bit are ADJACENT table entries
// (hash delta = +1 pre-mask), so each (oj,ok) corner-pair is ONE 16B
// load: 32 requests/thread instead of 64. Wrap (idx==0xFFFF, ~2^-16)
// is patched from a per-level uniform table[l][0] -- no OOB reads.
// No sched_barrier (latency is not the wall); nt loads/stores keep the
// streaming x/out traffic from thrashing the L2-resident 4MB table.

#define NPTS 524288
#define TTAB 65536
#define PI2 2654435761u
#define PI3 805459861u

typedef float vf2 __attribute__((ext_vector_type(2)));
typedef float vf4 __attribute__((ext_vector_type(4)));

// 16B load at 8B alignment (entries are float2-aligned).
__device__ __forceinline__ vf4 load16_a8(const float* p) {
    const float* pp = (const float*)__builtin_assume_aligned((const void*)p, 8);
    vf4 r;
    __builtin_memcpy(&r, pp, 16);
    return r;
}

__global__ __launch_bounds__(256) void ngp_kernel(
    const float* __restrict__ x,
    const float* __restrict__ gridp,
    const float* __restrict__ w0,
    const float* __restrict__ b0,
    const float* __restrict__ w1,
    const float* __restrict__ b1,
    const float* __restrict__ w2,
    const float* __restrict__ b2,
    float* __restrict__ out)
{
    // Weights staged in LDS; w0 transposed to [j][k] so the 16 inputs for
    // output-neuron j are contiguous (ds_read_b128). w1 rows contiguous.
    // All in-loop weight reads are wave-uniform -> LDS broadcast (free).
    __shared__ __align__(16) float sw0t[64 * 16];
    __shared__ __align__(16) float sw1[64 * 32];
    __shared__ __align__(16) float sw2t[64];   // [m][k] m=0,1 k=0..31
    __shared__ __align__(16) float sb0[64];
    __shared__ __align__(16) float sb1[32];
    __shared__ __align__(16) float sb2[2];

    const int tid = threadIdx.x;

    for (int i = tid; i < 64 * 16; i += 256) {
        int k = i >> 6, j = i & 63;          // w0 is (16,64) row-major: w0[k][j]
        sw0t[j * 16 + k] = w0[i];
    }
    for (int i = tid; i < 64 * 32; i += 256) sw1[i] = w1[i];
    if (tid < 64) {
        sw2t[(tid & 1) * 32 + (tid >> 1)] = w2[tid];  // w2 (32,2) -> w2t[m][k]
        sb0[tid] = b0[tid];
    }
    if (tid < 32) sb1[tid] = b1[tid];
    if (tid < 2)  sb2[tid] = b2[tid];
    __syncthreads();

    const int n = blockIdx.x * 256 + tid;
    const float px = __builtin_nontemporal_load(&x[n * 3 + 0]);
    const float py = __builtin_nontemporal_load(&x[n * 3 + 1]);
    const float pz = __builtin_nontemporal_load(&x[n * 3 + 2]);

    const float levels[8] = {2.0f, 2.6946f, 3.6301f, 4.8907f,
                             6.5893f, 8.8766f, 11.959f, 16.111f};

    // Per-level first entry (wrap patch source), wave-uniform scalar loads.
    vf2 first[8];
    #pragma unroll
    for (int l = 0; l < 8; ++l) {
        first[l].x = gridp[l * TTAB * 2 + 0];
        first[l].y = gridp[l * TTAB * 2 + 1];
    }

    // Encode: per level, 4 paired-corner 16B gathers + trilinear blend.
    vf2 enc2[8];
    #pragma unroll
    for (int l = 0; l < 8; ++l) {
        const float lev = levels[l];
        float xs0 = px * lev, xs1 = py * lev, xs2 = pz * lev;
        float fl0 = floorf(xs0), fl1 = floorf(xs1), fl2 = floorf(xs2);
        const float fx = xs0 - fl0, fy = xs1 - fl1, fz = xs2 - fl2;
        const float gx = 1.f - fx, gy = 1.f - fy, gz = 1.f - fz;
        unsigned cx = (unsigned)(int)fl0;
        unsigned cy = (unsigned)(int)fl1;
        unsigned cz = (unsigned)(int)fl2;
        const unsigned hbase = cx + cy * PI2 + cz * PI3;  // uint32 wrap = ref

        vf2 e = {0.f, 0.f};
        #pragma unroll
        for (int p = 0; p < 4; ++p) {
            const unsigned delta = ((p >> 1) ? PI2 : 0u) + ((p & 1) ? PI3 : 0u);
            unsigned b = (hbase + delta) & (TTAB - 1u);
            const bool wrap = (b == (TTAB - 1u));
            unsigned lidx = b - (wrap ? 1u : 0u);
            // entries {lidx, lidx+1} of level l in one 16B load (in-bounds:
            // lidx <= 0xFFFE).
            vf4 pr = load16_a8(gridp + ((unsigned)(l * TTAB) + lidx) * 2u);
            vf2 lo = {pr.x, pr.y}, hi = {pr.z, pr.w};
            vf2 c0 = wrap ? hi : lo;            // entry b   (x-offset 0)
            vf2 c1 = wrap ? first[l] : hi;      // entry b+1 mod T (x-offset 1)
            const float wyz = ((p >> 1) ? fy : gy) * ((p & 1) ? fz : gz);
            const float wl = gx * wyz, wr = fx * wyz;
            vf2 wlv = {wl, wl}, wrv = {wr, wr};
            e = __builtin_elementwise_fma(wlv, c0, e);
            e = __builtin_elementwise_fma(wrv, c1, e);
        }
        enc2[l] = e;
    }

    // Fused MLP: layer0 (16->64) + leaky, streamed into layer1 accumulators
    // (64->32, packed pairs) so h0 never materializes.
    vf2 h1[16];
    #pragma unroll
    for (int k = 0; k < 16; ++k) h1[k] = (vf2){0.f, 0.f};

    #pragma unroll 4
    for (int j = 0; j < 64; ++j) {
        const float4* __restrict__ wr0 = (const float4*)&sw0t[j * 16];
        float4 q0 = wr0[0], q1 = wr0[1], q2 = wr0[2], q3 = wr0[3];
        vf2 acc = {sb0[j], 0.f};
        acc = __builtin_elementwise_fma(enc2[0], (vf2){q0.x, q0.y}, acc);
        acc = __builtin_elementwise_fma(enc2[1], (vf2){q0.z, q0.w}, acc);
        acc = __builtin_elementwise_fma(enc2[2], (vf2){q1.x, q1.y}, acc);
        acc = __builtin_elementwise_fma(enc2[3], (vf2){q1.z, q1.w}, acc);
        acc = __builtin_elementwise_fma(enc2[4], (vf2){q2.x, q2.y}, acc);
        acc = __builtin_elementwise_fma(enc2[5], (vf2){q2.z, q2.w}, acc);
        acc = __builtin_elementwise_fma(enc2[6], (vf2){q3.x, q3.y}, acc);
        acc = __builtin_elementwise_fma(enc2[7], (vf2){q3.z, q3.w}, acc);
        float a = acc.x + acc.y;
        a = fmaf(0.01f, fminf(a, 0.f), fmaxf(a, 0.f));   // leaky_relu

        vf2 av = {a, a};
        const float4* __restrict__ w1r = (const float4*)&sw1[j * 32];
        #pragma unroll
        for (int k4 = 0; k4 < 8; ++k4) {
            float4 ww = w1r[k4];
            h1[k4 * 2 + 0] = __builtin_elementwise_fma(av, (vf2){ww.x, ww.y},
                                                       h1[k4 * 2 + 0]);
            h1[k4 * 2 + 1] = __builtin_elementwise_fma(av, (vf2){ww.z, ww.w},
                                                       h1[k4 * 2 + 1]);
        }
    }

    // Layer 2: 32 -> 2 (packed pairs, horizontal add at the end).
    const vf2* __restrict__ b1p = (const vf2*)sb1;
    const vf2* __restrict__ w20 = (const vf2*)&sw2t[0];
    const vf2* __restrict__ w21 = (const vf2*)&sw2t[32];
    vf2 s0v = {0.f, 0.f}, s1v = {0.f, 0.f};
    const vf2 zero2 = {0.f, 0.f};
    const vf2 slope2 = {0.01f, 0.01f};
    #pragma unroll
    for (int k = 0; k < 16; ++k) {
        vf2 hk = h1[k] + b1p[k];
        vf2 pos = __builtin_elementwise_max(hk, zero2);
        vf2 neg = __builtin_elementwise_min(hk, zero2);
        hk = __builtin_elementwise_fma(slope2, neg, pos);   // leaky_relu
        s0v = __builtin_elementwise_fma(hk, w20[k], s0v);
        s1v = __builtin_elementwise_fma(hk, w21[k], s1v);
    }
    float s0 = s0v.x + s0v.y + sb2[0];
    float s1 = s1v.x + s1v.y + sb2[1];

    // Epilogue: sigma clip, alpha scale, zeros. Non-temporal stores: out is
    // write-once streaming; keep it out of L2 so the table stays resident.
    __builtin_nontemporal_store((s0 > -1.0f) ? s0 : 0.0f, &out[n]);
    __builtin_nontemporal_store(fminf(0.0f, s1) * 0.1f, &out[NPTS + n]);
    __builtin_nontemporal_store(0.0f, &out[2 * NPTS + n]);
}

extern "C" void kernel_launch(void* const* d_in, const int* in_sizes, int n_in,
                              void* d_out, int out_size, void* d_ws, size_t ws_size,
                              hipStream_t stream) {
    const float* x    = (const float*)d_in[0];
    const float* grid = (const float*)d_in[1];
    const float* w0   = (const float*)d_in[2];
    const float* b0   = (const float*)d_in[3];
    const float* w1   = (const float*)d_in[4];
    const float* b1   = (const float*)d_in[5];
    const float* w2   = (const float*)d_in[6];
    const float* b2   = (const float*)d_in[7];
    float* out = (float*)d_out;

    ngp_kernel<<<NPTS / 256, 256, 0, stream>>>(x, grid, w0, b0, w1, b1, w2, b2, out);
}

// Round 7
// 160.213 us; speedup vs baseline: 1.4105x; 1.0022x over previous
//
#include <hip/hip_runtime.h>
#include <hip/hip_fp16.h>

// NGP hash-grid encode + fused MLP (16->64->32->2, leaky_relu 0.01)
// N=524288 points, L=8 levels, T=65536 table entries, F=2 features.
// Outputs (concat flat): sigma_clipped[N], alpha_scaled[N], zeros[N].
//
// R7: make the 32 paired gathers/thread L2 HITS. R5/R6 established the
// gather pipe is throughput-bound (~3.5 cyc/lane-request, invariant to
// concurrency) and FETCH_SIZE=23MB showed the 4MB fp32 table thrashes
// the 4MB-per-XCD L2 (refetched ~5x from L3/HBM). Pre-pass converts the
// grid to fp16 in d_ws (2MB table -> L2-resident; values in [0,0.01)
// so fp16 abs err <= ~2.5e-6/feature, well under the 1.38e-4 output
// threshold). Paired-corner gather shrinks 16B -> 8B. x-pairing trick
// (hash delta=+1 pre-mask for the x-offset bit) retained from R6.

#define NPTS 524288
#define TTAB 65536
#define PI2 2654435761u
#define PI3 805459861u

typedef float vf2 __attribute__((ext_vector_type(2)));
typedef float vf4 __attribute__((ext_vector_type(4)));

// Unaligned-tolerant loads (compiler picks a legal instruction).
__device__ __forceinline__ vf4 load16_a8(const float* p) {
    vf4 r; __builtin_memcpy(&r, p, 16); return r;
}
__device__ __forceinline__ uint2 load8_a4(const void* p) {
    uint2 r; __builtin_memcpy(&r, p, 8); return r;
}

// ---- Pre-pass: fp32 grid (4MB) -> fp16 table (2MB) in workspace ----
__global__ __launch_bounds__(256) void convert_grid(
    const float* __restrict__ g, __half* __restrict__ h)
{
    const int i = blockIdx.x * 256 + threadIdx.x;   // 262144 threads, 4 floats each
    const float4 v = ((const float4*)g)[i];
    union { __half2 h2[2]; uint2 u; } cv;
    cv.h2[0] = __floats2half2_rn(v.x, v.y);
    cv.h2[1] = __floats2half2_rn(v.z, v.w);
    ((uint2*)h)[i] = cv.u;
}

// ---- Main kernel (templated: fp16 table in ws, or fp32 fallback) ----
template <bool F16>
__global__ __launch_bounds__(256) void ngp_kernel(
    const float* __restrict__ x,
    const float* __restrict__ gridp,
    const float* __restrict__ w0,
    const float* __restrict__ b0,
    const float* __restrict__ w1,
    const float* __restrict__ b1,
    const float* __restrict__ w2,
    const float* __restrict__ b2,
    float* __restrict__ out,
    const __half* __restrict__ htab)
{
    // Weights staged in LDS; w0 transposed to [j][k] so the 16 inputs for
    // output-neuron j are contiguous (ds_read_b128). w1 rows contiguous.
    // All in-loop weight reads are wave-uniform -> LDS broadcast (free).
    __shared__ __align__(16) float sw0t[64 * 16];
    __shared__ __align__(16) float sw1[64 * 32];
    __shared__ __align__(16) float sw2t[64];   // [m][k] m=0,1 k=0..31
    __shared__ __align__(16) float sb0[64];
    __shared__ __align__(16) float sb1[32];
    __shared__ __align__(16) float sb2[2];

    const int tid = threadIdx.x;

    for (int i = tid; i < 64 * 16; i += 256) {
        int k = i >> 6, j = i & 63;          // w0 is (16,64) row-major: w0[k][j]
        sw0t[j * 16 + k] = w0[i];
    }
    for (int i = tid; i < 64 * 32; i += 256) sw1[i] = w1[i];
    if (tid < 64) {
        sw2t[(tid & 1) * 32 + (tid >> 1)] = w2[tid];  // w2 (32,2) -> w2t[m][k]
        sb0[tid] = b0[tid];
    }
    if (tid < 32) sb1[tid] = b1[tid];
    if (tid < 2)  sb2[tid] = b2[tid];
    __syncthreads();

    const int n = blockIdx.x * 256 + tid;
    const float px = __builtin_nontemporal_load(&x[n * 3 + 0]);
    const float py = __builtin_nontemporal_load(&x[n * 3 + 1]);
    const float pz = __builtin_nontemporal_load(&x[n * 3 + 2]);

    const float levels[8] = {2.0f, 2.6946f, 3.6301f, 4.8907f,
                             6.5893f, 8.8766f, 11.959f, 16.111f};

    // Per-level first entry (wrap patch source), wave-uniform scalar loads
    // from the exact fp32 grid (less error than the fp16 copy).
    vf2 first[8];
    #pragma unroll
    for (int l = 0; l < 8; ++l) {
        first[l].x = gridp[l * TTAB * 2 + 0];
        first[l].y = gridp[l * TTAB * 2 + 1];
    }

    // Encode: per level, 4 paired-corner gathers + trilinear blend.
    vf2 enc2[8];
    #pragma unroll
    for (int l = 0; l < 8; ++l) {
        const float lev = levels[l];
        float xs0 = px * lev, xs1 = py * lev, xs2 = pz * lev;
        float fl0 = floorf(xs0), fl1 = floorf(xs1), fl2 = floorf(xs2);
        const float fx = xs0 - fl0, fy = xs1 - fl1, fz = xs2 - fl2;
        const float gx = 1.f - fx, gy = 1.f - fy, gz = 1.f - fz;
        unsigned cx = (unsigned)(int)fl0;
        unsigned cy = (unsigned)(int)fl1;
        unsigned cz = (unsigned)(int)fl2;
        const unsigned hbase = cx + cy * PI2 + cz * PI3;  // uint32 wrap = ref

        vf2 e = {0.f, 0.f};
        #pragma unroll
        for (int p = 0; p < 4; ++p) {
            const unsigned delta = ((p >> 1) ? PI2 : 0u) + ((p & 1) ? PI3 : 0u);
            unsigned b = (hbase + delta) & (TTAB - 1u);
            const bool wrap = (b == (TTAB - 1u));
            unsigned lidx = b - (wrap ? 1u : 0u);   // <= 0xFFFE: pair in-bounds
            vf2 lo, hi;
            if constexpr (F16) {
                // entries {lidx, lidx+1}: 4 halves = 8B at 4B alignment
                uint2 pr = load8_a4((const unsigned char*)htab
                                    + (((unsigned)(l * TTAB) + lidx) << 2));
                union { unsigned u; __half2 h; } ul, uh;
                ul.u = pr.x; uh.u = pr.y;
                lo = (vf2){__low2float(ul.h), __high2float(ul.h)};
                hi = (vf2){__low2float(uh.h), __high2float(uh.h)};
            } else {
                vf4 pr = load16_a8(gridp + ((unsigned)(l * TTAB) + lidx) * 2u);
                lo = (vf2){pr.x, pr.y};
                hi = (vf2){pr.z, pr.w};
            }
            vf2 c0 = wrap ? hi : lo;            // entry b   (x-offset 0)
            vf2 c1 = wrap ? first[l] : hi;      // entry b+1 mod T (x-offset 1)
            const float wyz = ((p >> 1) ? fy : gy) * ((p & 1) ? fz : gz);
            const float wl = gx * wyz, wr = fx * wyz;
            vf2 wlv = {wl, wl}, wrv = {wr, wr};
            e = __builtin_elementwise_fma(wlv, c0, e);
            e = __builtin_elementwise_fma(wrv, c1, e);
        }
        enc2[l] = e;
    }

    // Fused MLP: layer0 (16->64) + leaky, streamed into layer1 accumulators
    // (64->32, packed pairs) so h0 never materializes.
    vf2 h1[16];
    #pragma unroll
    for (int k = 0; k < 16; ++k) h1[k] = (vf2){0.f, 0.f};

    #pragma unroll 4
    for (int j = 0; j < 64; ++j) {
        const float4* __restrict__ wr0 = (const float4*)&sw0t[j * 16];
        float4 q0 = wr0[0], q1 = wr0[1], q2 = wr0[2], q3 = wr0[3];
        vf2 acc = {sb0[j], 0.f};
        acc = __builtin_elementwise_fma(enc2[0], (vf2){q0.x, q0.y}, acc);
        acc = __builtin_elementwise_fma(enc2[1], (vf2){q0.z, q0.w}, acc);
        acc = __builtin_elementwise_fma(enc2[2], (vf2){q1.x, q1.y}, acc);
        acc = __builtin_elementwise_fma(enc2[3], (vf2){q1.z, q1.w}, acc);
        acc = __builtin_elementwise_fma(enc2[4], (vf2){q2.x, q2.y}, acc);
        acc = __builtin_elementwise_fma(enc2[5], (vf2){q2.z, q2.w}, acc);
        acc = __builtin_elementwise_fma(enc2[6], (vf2){q3.x, q3.y}, acc);
        acc = __builtin_elementwise_fma(enc2[7], (vf2){q3.z, q3.w}, acc);
        float a = acc.x + acc.y;
        a = fmaf(0.01f, fminf(a, 0.f), fmaxf(a, 0.f));   // leaky_relu

        vf2 av = {a, a};
        const float4* __restrict__ w1r = (const float4*)&sw1[j * 32];
        #pragma unroll
        for (int k4 = 0; k4 < 8; ++k4) {
            float4 ww = w1r[k4];
            h1[k4 * 2 + 0] = __builtin_elementwise_fma(av, (vf2){ww.x, ww.y},
                                                       h1[k4 * 2 + 0]);
            h1[k4 * 2 + 1] = __builtin_elementwise_fma(av, (vf2){ww.z, ww.w},
                                                       h1[k4 * 2 + 1]);
        }
    }

    // Layer 2: 32 -> 2 (packed pairs, horizontal add at the end).
    const vf2* __restrict__ b1p = (const vf2*)sb1;
    const vf2* __restrict__ w20 = (const vf2*)&sw2t[0];
    const vf2* __restrict__ w21 = (const vf2*)&sw2t[32];
    vf2 s0v = {0.f, 0.f}, s1v = {0.f, 0.f};
    const vf2 zero2 = {0.f, 0.f};
    const vf2 slope2 = {0.01f, 0.01f};
    #pragma unroll
    for (int k = 0; k < 16; ++k) {
        vf2 hk = h1[k] + b1p[k];
        vf2 pos = __builtin_elementwise_max(hk, zero2);
        vf2 neg = __builtin_elementwise_min(hk, zero2);
        hk = __builtin_elementwise_fma(slope2, neg, pos);   // leaky_relu
        s0v = __builtin_elementwise_fma(hk, w20[k], s0v);
        s1v = __builtin_elementwise_fma(hk, w21[k], s1v);
    }
    float s0 = s0v.x + s0v.y + sb2[0];
    float s1 = s1v.x + s1v.y + sb2[1];

    // Epilogue: sigma clip, alpha scale, zeros. Non-temporal stores: out is
    // write-once streaming; keep L2 for the table.
    __builtin_nontemporal_store((s0 > -1.0f) ? s0 : 0.0f, &out[n]);
    __builtin_nontemporal_store(fminf(0.0f, s1) * 0.1f, &out[NPTS + n]);
    __builtin_nontemporal_store(0.0f, &out[2 * NPTS + n]);
}

extern "C" void kernel_launch(void* const* d_in, const int* in_sizes, int n_in,
                              void* d_out, int out_size, void* d_ws, size_t ws_size,
                              hipStream_t stream) {
    const float* x    = (const float*)d_in[0];
    const float* grid = (const float*)d_in[1];
    const float* w0   = (const float*)d_in[2];
    const float* b0   = (const float*)d_in[3];
    const float* w1   = (const float*)d_in[4];
    const float* b1   = (const float*)d_in[5];
    const float* w2   = (const float*)d_in[6];
    const float* b2   = (const float*)d_in[7];
    float* out = (float*)d_out;

    const size_t tab_bytes = (size_t)8 * TTAB * 2 * sizeof(__half);  // 2MB
    if (ws_size >= tab_bytes) {
        __half* htab = (__half*)d_ws;
        // 1,048,576 floats, 4 per thread -> 262144 threads -> 1024 blocks
        convert_grid<<<1024, 256, 0, stream>>>(grid, htab);
        ngp_kernel<true><<<NPTS / 256, 256, 0, stream>>>(
            x, grid, w0, b0, w1, b1, w2, b2, out, htab);
    } else {
        ngp_kernel<false><<<NPTS / 256, 256, 0, stream>>>(
            x, grid, w0, b0, w1, b1, w2, b2, out, nullptr);
    }
}

// Round 8
// 151.012 us; speedup vs baseline: 1.4964x; 1.0609x over previous
//
#include <hip/hip_runtime.h>
#include <hip/hip_fp16.h>

// NGP hash-grid encode + fused MLP (16->64->32->2, leaky_relu 0.01)
// N=524288 points, L=8 levels, T=65536 table entries, F=2 features.
// Outputs (concat flat): sigma_clipped[N], alpha_scaled[N], zeros[N].
//
// R8: the gather pipe is request-slot bound (~0.3 lane-req/cyc/CU,
// invariant to size/concurrency; R5/R6/R7 evidence) with a ~78us floor
// at 32 req/thread. Remaining slack is the non-overlapped MLP phase.
// This round: (a) NO LDS -- weights read via wave-uniform addresses
// straight from global => compiler emits s_load through the scalar K$
// (12.7KB fits), MLP becomes v_fmac_f32 v,s,v with zero LDS/VMEM issue,
// no staging, no syncthreads; (b) all 32 fp16 pair-gathers in flight
// (8B each = 64 VGPRs payload, no R5 occupancy collapse) forced live
// with sched_barrier(0) (mechanism verified in R5).

#define NPTS 524288
#define TTAB 65536
#define PI2 2654435761u
#define PI3 805459861u

typedef float vf2 __attribute__((ext_vector_type(2)));
typedef float vf4 __attribute__((ext_vector_type(4)));

__device__ __forceinline__ vf4 load16_a8(const float* p) {
    vf4 r; __builtin_memcpy(&r, p, 16); return r;
}
__device__ __forceinline__ uint2 load8_a4(const void* p) {
    uint2 r; __builtin_memcpy(&r, p, 8); return r;
}

// ---- Pre-pass: fp32 grid (4MB) -> fp16 table (2MB) in workspace ----
__global__ __launch_bounds__(256) void convert_grid(
    const float* __restrict__ g, __half* __restrict__ h)
{
    const int i = blockIdx.x * 256 + threadIdx.x;   // 262144 threads, 4 floats each
    const float4 v = ((const float4*)g)[i];
    union { __half2 h2[2]; uint2 u; } cv;
    cv.h2[0] = __floats2half2_rn(v.x, v.y);
    cv.h2[1] = __floats2half2_rn(v.z, v.w);
    ((uint2*)h)[i] = cv.u;
}

// ---- Main kernel (F16: fp16 table in ws; else fp32 per-level path) ----
template <bool F16>
__global__ __launch_bounds__(256) void ngp_kernel(
    const float* __restrict__ x,
    const float* __restrict__ gridp,
    const float* __restrict__ w0,
    const float* __restrict__ b0,
    const float* __restrict__ w1,
    const float* __restrict__ b1,
    const float* __restrict__ w2,
    const float* __restrict__ b2,
    float* __restrict__ out,
    const __half* __restrict__ htab)
{
    const int n = blockIdx.x * 256 + threadIdx.x;
    const float px = __builtin_nontemporal_load(&x[n * 3 + 0]);
    const float py = __builtin_nontemporal_load(&x[n * 3 + 1]);
    const float pz = __builtin_nontemporal_load(&x[n * 3 + 2]);

    const float levels[8] = {2.0f, 2.6946f, 3.6301f, 4.8907f,
                             6.5893f, 8.8766f, 11.959f, 16.111f};

    // Phase 1: all hash bases + fractions (pure VALU).
    float fxs[8], fys[8], fzs[8];
    unsigned hb[8];
    #pragma unroll
    for (int l = 0; l < 8; ++l) {
        const float lev = levels[l];
        float xs0 = px * lev, xs1 = py * lev, xs2 = pz * lev;
        float fl0 = floorf(xs0), fl1 = floorf(xs1), fl2 = floorf(xs2);
        fxs[l] = xs0 - fl0;
        fys[l] = xs1 - fl1;
        fzs[l] = xs2 - fl2;
        unsigned cx = (unsigned)(int)fl0;
        unsigned cy = (unsigned)(int)fl1;
        unsigned cz = (unsigned)(int)fl2;
        hb[l] = cx + cy * PI2 + cz * PI3;   // uint32 wrap = ref semantics
    }

    vf2 enc2[8];

    if constexpr (F16) {
        // Phase 2: issue all 32 paired-corner 8B gathers (x-pair trick:
        // the x-offset bit is hash delta +1 pre-mask -> adjacent entries).
        uint2 praw[32];
        #pragma unroll
        for (int l = 0; l < 8; ++l) {
            #pragma unroll
            for (int p = 0; p < 4; ++p) {
                const unsigned delta = ((p >> 1) ? PI2 : 0u)
                                     + ((p & 1) ? PI3 : 0u);
                unsigned b = (hb[l] + delta) & (TTAB - 1u);
                unsigned lidx = b - ((b == (TTAB - 1u)) ? 1u : 0u);
                praw[l * 4 + p] = load8_a4((const unsigned char*)htab
                                  + (((unsigned)(l * TTAB) + lidx) << 2));
            }
        }

        // MIR fence: loads above stay issued & live; consumers below.
        __builtin_amdgcn_sched_barrier(0);

        // Phase 3: convert, wrap-patch, trilinear blend.
        #pragma unroll
        for (int l = 0; l < 8; ++l) {
            const float fx = fxs[l], fy = fys[l], fz = fzs[l];
            const float gx = 1.f - fx, gy = 1.f - fy, gz = 1.f - fz;
            // wrap patch source: level-l entry 0 (uniform -> s_load, exact)
            const vf2 first = {gridp[l * TTAB * 2 + 0],
                               gridp[l * TTAB * 2 + 1]};
            vf2 e = {0.f, 0.f};
            #pragma unroll
            for (int p = 0; p < 4; ++p) {
                const unsigned delta = ((p >> 1) ? PI2 : 0u)
                                     + ((p & 1) ? PI3 : 0u);
                unsigned b = (hb[l] + delta) & (TTAB - 1u);
                const bool wrap = (b == (TTAB - 1u));
                uint2 pr = praw[l * 4 + p];
                union { unsigned u; __half2 h; } ul, uh;
                ul.u = pr.x; uh.u = pr.y;
                vf2 lo = {__low2float(ul.h), __high2float(ul.h)};
                vf2 hi = {__low2float(uh.h), __high2float(uh.h)};
                vf2 c0 = wrap ? hi : lo;        // entry b   (x-offset 0)
                vf2 c1 = wrap ? first : hi;     // entry b+1 mod T (x-offset 1)
                const float wyz = ((p >> 1) ? fy : gy) * ((p & 1) ? fz : gz);
                const float wl = gx * wyz, wr = fx * wyz;
                e = __builtin_elementwise_fma((vf2){wl, wl}, c0, e);
                e = __builtin_elementwise_fma((vf2){wr, wr}, c1, e);
            }
            enc2[l] = e;
        }
    } else {
        // Fallback (ws too small): fp32 per-level paired gathers (R6 path).
        #pragma unroll
        for (int l = 0; l < 8; ++l) {
            const float fx = fxs[l], fy = fys[l], fz = fzs[l];
            const float gx = 1.f - fx, gy = 1.f - fy, gz = 1.f - fz;
            const vf2 first = {gridp[l * TTAB * 2 + 0],
                               gridp[l * TTAB * 2 + 1]};
            vf2 e = {0.f, 0.f};
            #pragma unroll
            for (int p = 0; p < 4; ++p) {
                const unsigned delta = ((p >> 1) ? PI2 : 0u)
                                     + ((p & 1) ? PI3 : 0u);
                unsigned b = (hb[l] + delta) & (TTAB - 1u);
                const bool wrap = (b == (TTAB - 1u));
                unsigned lidx = b - (wrap ? 1u : 0u);
                vf4 pr = load16_a8(gridp + ((unsigned)(l * TTAB) + lidx) * 2u);
                vf2 lo = {pr.x, pr.y}, hi = {pr.z, pr.w};
                vf2 c0 = wrap ? hi : lo;
                vf2 c1 = wrap ? first : hi;
                const float wyz = ((p >> 1) ? fy : gy) * ((p & 1) ? fz : gz);
                const float wl = gx * wyz, wr = fx * wyz;
                e = __builtin_elementwise_fma((vf2){wl, wl}, c0, e);
                e = __builtin_elementwise_fma((vf2){wr, wr}, c1, e);
            }
            enc2[l] = e;
        }
    }

    float enc[16];
    #pragma unroll
    for (int l = 0; l < 8; ++l) { enc[2 * l] = enc2[l].x; enc[2 * l + 1] = enc2[l].y; }

    // Fused MLP, scalar-weight form: every weight/bias address is
    // wave-uniform -> s_load through the scalar K$ (12.7KB total, fits).
    // v_fmac_f32 vdst, s_w, v_enc: no LDS, no vector loads, no sync.
    float h1[32];
    #pragma unroll
    for (int k = 0; k < 32; ++k) h1[k] = 0.f;

    #pragma unroll 2
    for (int j = 0; j < 64; ++j) {
        float a = b0[j];
        #pragma unroll
        for (int k = 0; k < 16; ++k)
            a = fmaf(w0[k * 64 + j], enc[k], a);     // w0 (16,64): column j
        a = fmaf(0.01f, fminf(a, 0.f), fmaxf(a, 0.f));   // leaky_relu

        #pragma unroll
        for (int k = 0; k < 32; ++k)
            h1[k] = fmaf(w1[j * 32 + k], a, h1[k]);  // w1 (64,32): row j
    }

    // Layer 2: 32 -> 2, scalar weights.
    float s0 = b2[0], s1 = b2[1];
    #pragma unroll
    for (int k = 0; k < 32; ++k) {
        float hk = h1[k] + b1[k];
        hk = fmaf(0.01f, fminf(hk, 0.f), fmaxf(hk, 0.f));   // leaky_relu
        s0 = fmaf(hk, w2[k * 2 + 0], s0);
        s1 = fmaf(hk, w2[k * 2 + 1], s1);
    }

    // Epilogue: sigma clip, alpha scale, zeros. nt stores keep the
    // streaming output out of L2 so the table stays resident.
    __builtin_nontemporal_store((s0 > -1.0f) ? s0 : 0.0f, &out[n]);
    __builtin_nontemporal_store(fminf(0.0f, s1) * 0.1f, &out[NPTS + n]);
    __builtin_nontemporal_store(0.0f, &out[2 * NPTS + n]);
}

extern "C" void kernel_launch(void* const* d_in, const int* in_sizes, int n_in,
                              void* d_out, int out_size, void* d_ws, size_t ws_size,
                              hipStream_t stream) {
    const float* x    = (const float*)d_in[0];
    const float* grid = (const float*)d_in[1];
    const float* w0   = (const float*)d_in[2];
    const float* b0   = (const float*)d_in[3];
    const float* w1   = (const float*)d_in[4];
    const float* b1   = (const float*)d_in[5];
    const float* w2   = (const float*)d_in[6];
    const float* b2   = (const float*)d_in[7];
    float* out = (float*)d_out;

    const size_t tab_bytes = (size_t)8 * TTAB * 2 * sizeof(__half);  // 2MB
    if (ws_size >= tab_bytes) {
        __half* htab = (__half*)d_ws;
        convert_grid<<<1024, 256, 0, stream>>>(grid, htab);
        ngp_kernel<true><<<NPTS / 256, 256, 0, stream>>>(
            x, grid, w0, b0, w1, b1, w2, b2, out, htab);
    } else {
        ngp_kernel<false><<<NPTS / 256, 256, 0, stream>>>(
            x, grid, w0, b0, w1, b1, w2, b2, out, nullptr);
    }
}